// Round 1
// baseline (978.422 us; speedup 1.0000x reference)
//
#include <hip/hip_runtime.h>
#include <hip/hip_bf16.h>
#include <cstdint>
#include <cstdio>

// Problem constants
// B=16, S=2048, H=1024, D=16, T=5;  M = B*S = 32768, N = 2H = 2048, K = 1024.

typedef float f32x4 __attribute__((ext_vector_type(4)));
typedef __bf16 bf8v __attribute__((ext_vector_type(8)));

// d_ws byte offsets
#define WS_ABF   0ULL                 // 32768*1024*2  = 67,108,864   (hidden as bf16)
#define WS_WBF   67108864ULL          // 2048*1024*2   = 4,194,304    (W_proj as bf16)
#define WS_PROJ  71303168ULL          // 32768*2048*2  = 134,217,728  (proj = [h_all|v_all] bf16)
#define WS_OP4   205520896ULL         // 32768*16      = 524,288      (op_probs padded float4)
#define WS_WPTR  206045184ULL         // 16*2048*16*4  = 2,097,152    (w = push*p_push)
#define WS_PPTR  208142336ULL         // 16*2048*16*4  = 2,097,152    (new_p)
#define WS_NEED  210239488ULL

// d_out float offsets
#define OUT_FINAL 0
#define OUT_STACK 33554432ULL         // (16,16,1024)
#define OUT_PTR   33816576ULL         // (16,16)
#define OUT_TOOLW 33816832ULL         // (16,2048,5)

__device__ __forceinline__ float bf2f(unsigned short u) {
    union { unsigned int i; float f; } v; v.i = ((unsigned int)u) << 16; return v.f;
}
__device__ __forceinline__ unsigned short f2bf(float f) {
    __hip_bfloat16 h = __float2bfloat16(f);
    return __builtin_bit_cast(unsigned short, h);
}
template<int C>
__device__ __forceinline__ float fdpp(float x) {
    return __int_as_float(__builtin_amdgcn_mov_dpp(__float_as_int(x), C, 0xF, 0xF, true));
}
__device__ __forceinline__ void gload_lds16(const void* g, void* l) {
    __builtin_amdgcn_global_load_lds(
        (__attribute__((address_space(1))) void*)(uintptr_t)g,
        (__attribute__((address_space(3))) void*)l,
        16, 0, 0);
}

// ---------------------------------------------------------------------------
// k0: convert hidden -> bf16 (A), W_proj -> bf16 (B), and op_probs (f32).
// blocks 0..8191: one wave per hidden row (4 rows/block). blocks 8192..9215: W convert.
// ---------------------------------------------------------------------------
__global__ __launch_bounds__(256) void k0(const float* __restrict__ hid,
                                          const float* __restrict__ Wp,
                                          const float* __restrict__ Wop,
                                          const float* __restrict__ bop,
                                          unsigned short* __restrict__ Abf,
                                          unsigned short* __restrict__ Wbf,
                                          float4* __restrict__ op4)
{
    const int bid = blockIdx.x, tid = threadIdx.x;
    if (bid < 8192) {
        const int wid = tid >> 6, lane = tid & 63;
        const int row = bid * 4 + wid;
        const float* hrow = hid + (size_t)row * 1024 + lane * 16;
        float xs[16];
        #pragma unroll
        for (int j = 0; j < 4; ++j) {
            float4 t = *(const float4*)(hrow + j * 4);
            xs[j*4+0] = t.x; xs[j*4+1] = t.y; xs[j*4+2] = t.z; xs[j*4+3] = t.w;
        }
        unsigned short us[16];
        #pragma unroll
        for (int j = 0; j < 16; ++j) us[j] = f2bf(xs[j]);
        uint4 ulo, uhi;
        ulo.x = (unsigned)us[0]  | ((unsigned)us[1]  << 16);
        ulo.y = (unsigned)us[2]  | ((unsigned)us[3]  << 16);
        ulo.z = (unsigned)us[4]  | ((unsigned)us[5]  << 16);
        ulo.w = (unsigned)us[6]  | ((unsigned)us[7]  << 16);
        uhi.x = (unsigned)us[8]  | ((unsigned)us[9]  << 16);
        uhi.y = (unsigned)us[10] | ((unsigned)us[11] << 16);
        uhi.z = (unsigned)us[12] | ((unsigned)us[13] << 16);
        uhi.w = (unsigned)us[14] | ((unsigned)us[15] << 16);
        unsigned short* arow = Abf + (size_t)row * 1024 + lane * 16;
        *(uint4*)(arow)     = ulo;
        *(uint4*)(arow + 8) = uhi;
        // op logits in f32 (feeds sharpening recurrence -> keep precise)
        float pt[3] = {0.f, 0.f, 0.f};
        #pragma unroll
        for (int o = 0; o < 3; ++o) {
            const float* wrow = Wop + o * 1024 + lane * 16;
            #pragma unroll
            for (int j = 0; j < 4; ++j) {
                float4 t = *(const float4*)(wrow + j * 4);
                pt[o] += xs[j*4+0]*t.x + xs[j*4+1]*t.y + xs[j*4+2]*t.z + xs[j*4+3]*t.w;
            }
        }
        #pragma unroll
        for (int o = 0; o < 3; ++o)
            #pragma unroll
            for (int m = 32; m >= 1; m >>= 1) pt[o] += __shfl_xor(pt[o], m);
        if (lane == 0) {
            float l0 = pt[0] + bop[0], l1 = pt[1] + bop[1], l2 = pt[2] + bop[2];
            float mx = fmaxf(l0, fmaxf(l1, l2));
            float e0 = expf(l0 - mx), e1 = expf(l1 - mx), e2 = expf(l2 - mx);
            float inv = 1.0f / (e0 + e1 + e2);
            float4 r; r.x = e0 * inv; r.y = e1 * inv; r.z = e2 * inv; r.w = 0.f;
            op4[row] = r;
        }
    } else {
        const int b2 = bid - 8192;
        const size_t base = (size_t)b2 * 2048 + tid * 8;
        float4 a = *(const float4*)(Wp + base);
        float4 b = *(const float4*)(Wp + base + 4);
        unsigned short vs[8] = { f2bf(a.x), f2bf(a.y), f2bf(a.z), f2bf(a.w),
                                 f2bf(b.x), f2bf(b.y), f2bf(b.z), f2bf(b.w) };
        uint4 u;
        u.x = (unsigned)vs[0] | ((unsigned)vs[1] << 16);
        u.y = (unsigned)vs[2] | ((unsigned)vs[3] << 16);
        u.z = (unsigned)vs[4] | ((unsigned)vs[5] << 16);
        u.w = (unsigned)vs[6] | ((unsigned)vs[7] << 16);
        *(uint4*)(Wbf + base) = u;
    }
}

// ---------------------------------------------------------------------------
// k1: fused launch. blocks 0..15: pointer scan (1 batch each, DPP over 16 lanes).
//     blocks 16..4111: bf16 MFMA GEMM, 128x128 tile, BK=64, st_16x32 LDS swizzle,
//     global_load_lds width-16 staging (m97/m201 recipe).
// ---------------------------------------------------------------------------
__global__ __launch_bounds__(256) void k1(const unsigned short* __restrict__ Abf,
                                          const unsigned short* __restrict__ Wbf,
                                          const float* __restrict__ bproj,
                                          unsigned short* __restrict__ proj,
                                          const float4* __restrict__ op4,
                                          float* __restrict__ wbuf,
                                          float* __restrict__ pbuf,
                                          float* __restrict__ out)
{
    __shared__ uint4 sm[2048];   // 32 KiB: GEMM A|B tiles, or scan's op_probs cache
    const int bid = blockIdx.x, tid = threadIdx.x;

    if (bid < 16) {
        // ---- pointer scan, one batch per block ----
        const int b = bid;
        #pragma unroll
        for (int i = 0; i < 8; ++i)
            sm[tid + i * 256] = ((const uint4*)op4)[(size_t)b * 2048 + tid + i * 256];
        __syncthreads();
        if (tid >= 64) return;               // wave 0 only from here; no more barriers
        __builtin_amdgcn_s_setprio(3);       // win SIMD arbitration vs co-resident GEMM waves
        const int lane = tid, d = lane & 15;
        // runtime probe of DPP rotate direction (row_ror:1 == src[(i-1)&15] expected)
        const float probe = (float)d;
        const bool ror1_is_push = (fdpp<0x121>(probe) == (float)((d + 15) & 15));
        float p = (d == 0) ? 1.0f : 0.0f;
        const float4* smf = (const float4*)sm;
        float4 o0 = smf[0], o1 = smf[1];
        float* wb = wbuf + (size_t)b * 2048 * 16;
        float* pb = pbuf + (size_t)b * 2048 * 16;
        for (int s = 0; s < 2048; ++s) {
            float4 o2 = smf[(s + 2 < 2048) ? (s + 2) : 2047];
            const float push = o0.x, pop = o0.y, nop = o0.z;
            const float ra = fdpp<0x121>(p);
            const float rb = fdpp<0x12F>(p);
            const float ppush = ror1_is_push ? ra : rb;   // p[d-1]
            const float ppop  = ror1_is_push ? rb : ra;   // p[d+1]
            const float w = push * ppush;
            float lin = push * ppush + pop * ppop + nop * p;
            float x2 = lin * lin;
            float x5 = x2 * x2 * lin;
            float sum = x5;
            sum += fdpp<0x128>(sum);
            sum += fdpp<0x124>(sum);
            sum += fdpp<0x122>(sum);
            sum += fdpp<0x121>(sum);
            float pn = x5 / (sum + 1e-8f);
            if (lane < 16) {
                wb[s * 16 + d] = w;
                pb[s * 16 + d] = pn;
            }
            p = pn;
            o0 = o1; o1 = o2;
        }
        if (lane < 16) out[OUT_PTR + (size_t)b * 16 + d] = p;
        return;
    }

    // ---- GEMM: proj[m, n] = sum_k A[m,k] * W[n,k] + b_proj[n]  (both K-contiguous) ----
    const int bid2 = bid - 16;
    const int gm = bid2 & 255;          // 256 m-tiles (m fastest: neighbors share B panel)
    const int gn = bid2 >> 8;           // 16 n-tiles
    const int wid = tid >> 6, lane = tid & 63;
    const int wm = wid & 1, wn = wid >> 1;     // 2x2 waves of 64x64
    const size_t row0 = (size_t)gm * 128;
    const size_t col0 = (size_t)gn * 128;
    char* smc = (char*)sm;
    const char* Ab = (const char*)Abf;
    const char* Bb = (const char*)Wbf;
    f32x4 acc[4][4];
    const f32x4 z = {0.f, 0.f, 0.f, 0.f};
    #pragma unroll
    for (int i = 0; i < 4; ++i)
        #pragma unroll
        for (int j = 0; j < 4; ++j) acc[i][j] = z;

    for (int kt = 0; kt < 16; ++kt) {
        // stage A(128x64 bf16) and B(128x64 bf16); linear LDS dest, inverse-swizzled source
        #pragma unroll
        for (int i = 0; i < 4; ++i) {
            const int off  = (i * 256 + tid) * 16;
            const int soff = off ^ (((off >> 9) & 1) << 5);
            gload_lds16(Ab + (row0 + (size_t)(soff >> 7)) * 2048 + (size_t)kt * 128 + (soff & 127),
                        smc + (i * 256 + wid * 64) * 16);
        }
        #pragma unroll
        for (int i = 0; i < 4; ++i) {
            const int off  = (i * 256 + tid) * 16;
            const int soff = off ^ (((off >> 9) & 1) << 5);
            gload_lds16(Bb + (col0 + (size_t)(soff >> 7)) * 2048 + (size_t)kt * 128 + (soff & 127),
                        smc + 16384 + (i * 256 + wid * 64) * 16);
        }
        __syncthreads();
        bf8v af[4][2], bfv[4][2];
        #pragma unroll
        for (int mr = 0; mr < 4; ++mr)
            #pragma unroll
            for (int kk = 0; kk < 2; ++kk) {
                int byt = (wm * 64 + mr * 16 + (lane & 15)) * 128 + kk * 64 + ((lane >> 4) * 16);
                byt ^= ((byt >> 9) & 1) << 5;
                af[mr][kk] = *(const bf8v*)(smc + byt);
            }
        #pragma unroll
        for (int nr = 0; nr < 4; ++nr)
            #pragma unroll
            for (int kk = 0; kk < 2; ++kk) {
                int byt = (wn * 64 + nr * 16 + (lane & 15)) * 128 + kk * 64 + ((lane >> 4) * 16);
                byt ^= ((byt >> 9) & 1) << 5;
                bfv[nr][kk] = *(const bf8v*)(smc + 16384 + byt);
            }
        #pragma unroll
        for (int mr = 0; mr < 4; ++mr)
            #pragma unroll
            for (int nr = 0; nr < 4; ++nr) {
                acc[mr][nr] = __builtin_amdgcn_mfma_f32_16x16x32_bf16(af[mr][0], bfv[nr][0], acc[mr][nr], 0, 0, 0);
                acc[mr][nr] = __builtin_amdgcn_mfma_f32_16x16x32_bf16(af[mr][1], bfv[nr][1], acc[mr][nr], 0, 0, 0);
            }
        __syncthreads();
    }
    // epilogue: C/D layout col = lane&15, row = (lane>>4)*4 + j  [m89-verified]
    #pragma unroll
    for (int mr = 0; mr < 4; ++mr) {
        const int rloc = wm * 64 + mr * 16 + ((lane >> 4) * 4);
        #pragma unroll
        for (int nr = 0; nr < 4; ++nr) {
            const size_t col = col0 + wn * 64 + nr * 16 + (lane & 15);
            const float bias = bproj[col];
            #pragma unroll
            for (int j = 0; j < 4; ++j)
                proj[(row0 + rloc + j) * 2048 + col] = f2bf(acc[mr][nr][j] + bias);
        }
    }
}

// ---------------------------------------------------------------------------
// k4: stack scan. 64 blocks = 16 batches x 4 h-chunks of 256. Thread owns one h,
//     16 stack regs. v_all staged via LDS 64-step chunks; w/p are block-uniform
//     loads (expect s_load scalarization). tops -> d_out final region (scratch).
// ---------------------------------------------------------------------------
__global__ __launch_bounds__(256) void k4(const unsigned short* __restrict__ proj,
                                          const float* __restrict__ wbuf,
                                          const float* __restrict__ pbuf,
                                          float* __restrict__ out)
{
    __shared__ uint4 sm[2048];  // 64 steps x 256 h x bf16 = 32 KiB
    const int bid = blockIdx.x, tid = threadIdx.x;
    const int b = bid >> 2, hc = bid & 3;
    const int h = hc * 256 + tid;
    float st[16];
    #pragma unroll
    for (int d = 0; d < 16; ++d) st[d] = 0.f;
    const float* wb = wbuf + (size_t)b * 2048 * 16;
    const float* pb = pbuf + (size_t)b * 2048 * 16;
    float* topout = out + (size_t)b * 2048 * 1024 + h;
    const char* vbase = (const char*)proj + ((size_t)b * 2048 * 2048 + 1024 + hc * 256) * 2;
    const unsigned short* smu = (const unsigned short*)sm;
    for (int c = 0; c < 32; ++c) {
        __syncthreads();
        #pragma unroll
        for (int i = 0; i < 8; ++i) {
            const int idx = tid + i * 256;
            const int r = idx >> 5, q = idx & 31;
            sm[idx] = *(const uint4*)(vbase + (size_t)(c * 64 + r) * 4096 + q * 16);
        }
        __syncthreads();
        #pragma unroll 2
        for (int r = 0; r < 64; ++r) {
            const int s = c * 64 + r;
            const float v = bf2f(smu[r * 256 + tid]);
            const float* wr = wb + s * 16;
            const float* pr = pb + s * 16;
            float t0 = 0.f, t1 = 0.f, t2 = 0.f, t3 = 0.f;
            #pragma unroll
            for (int d = 0; d < 16; d += 4) {
                st[d+0] += wr[d+0] * (v - st[d+0]); t0 += pr[d+0] * st[d+0];
                st[d+1] += wr[d+1] * (v - st[d+1]); t1 += pr[d+1] * st[d+1];
                st[d+2] += wr[d+2] * (v - st[d+2]); t2 += pr[d+2] * st[d+2];
                st[d+3] += wr[d+3] * (v - st[d+3]); t3 += pr[d+3] * st[d+3];
            }
            topout[(size_t)s * 1024] = (t0 + t1) + (t2 + t3);
        }
    }
    #pragma unroll
    for (int d = 0; d < 16; ++d)
        out[OUT_STACK + ((size_t)b * 16 + d) * 1024 + h] = st[d];
}

// ---------------------------------------------------------------------------
// k5: epilogue. One block per (b,s) row: tool logits + softmax, apply tools,
//     combined = h_all + processed + hidden, LayerNorm. In-place over tops.
// ---------------------------------------------------------------------------
__global__ __launch_bounds__(256) void k5(const unsigned short* __restrict__ proj,
                                          const float* __restrict__ hid,
                                          const float* __restrict__ Wtool,
                                          const float* __restrict__ btool,
                                          const float* __restrict__ gamma,
                                          const float* __restrict__ beta,
                                          float* __restrict__ out)
{
    __shared__ float red[4][8];
    const int row = blockIdx.x, tid = threadIdx.x;
    const int wid = tid >> 6, lane = tid & 63;
    const int k0i = tid * 4;
    const unsigned short* hrow = proj + (size_t)row * 2048 + k0i;
    float hh[4];
    hh[0] = bf2f(hrow[0]); hh[1] = bf2f(hrow[1]); hh[2] = bf2f(hrow[2]); hh[3] = bf2f(hrow[3]);
    float4 tp  = *(const float4*)(out + (size_t)row * 1024 + k0i);   // tops (scratch)
    float4 hd4 = *(const float4*)(hid + (size_t)row * 1024 + k0i);
    float xs[4]  = {tp.x, tp.y, tp.z, tp.w};
    float hds[4] = {hd4.x, hd4.y, hd4.z, hd4.w};
    float pt[5];
    #pragma unroll
    for (int t = 0; t < 5; ++t) {
        float4 wv = *(const float4*)(Wtool + t * 1024 + k0i);
        pt[t] = hh[0]*wv.x + hh[1]*wv.y + hh[2]*wv.z + hh[3]*wv.w;
    }
    #pragma unroll
    for (int t = 0; t < 5; ++t)
        #pragma unroll
        for (int m = 32; m >= 1; m >>= 1) pt[t] += __shfl_xor(pt[t], m);
    if (lane == 0) {
        #pragma unroll
        for (int t = 0; t < 5; ++t) red[wid][t] = pt[t];
    }
    __syncthreads();
    float tw[5];
    {
        float lg[5];
        #pragma unroll
        for (int t = 0; t < 5; ++t)
            lg[t] = red[0][t] + red[1][t] + red[2][t] + red[3][t] + btool[t];
        float mx = fmaxf(fmaxf(fmaxf(lg[0], lg[1]), fmaxf(lg[2], lg[3])), lg[4]);
        float se = 0.f;
        #pragma unroll
        for (int t = 0; t < 5; ++t) { tw[t] = expf(lg[t] - mx); se += tw[t]; }
        float inv = 1.0f / se;
        #pragma unroll
        for (int t = 0; t < 5; ++t) tw[t] *= inv;
    }
    if (tid < 5) out[OUT_TOOLW + (size_t)row * 5 + tid] = tw[tid];
    float cj[4];
    #pragma unroll
    for (int j = 0; j < 4; ++j) {
        const float x = xs[j];
        const float rl = fmaxf(x, 0.f);
        const float gl = 0.5f * x * (1.f + erff(x * 0.70710678118654752f));  // exact gelu
        const float th = tanhf(x);
        const float sg = 1.f / (1.f + expf(-x));
        const float pr = rl*tw[0] + gl*tw[1] + th*tw[2] + sg*tw[3] + x*tw[4];
        cj[j] = hh[j] + pr + hds[j];
    }
    float s1 = cj[0] + cj[1] + cj[2] + cj[3];
    float s2 = cj[0]*cj[0] + cj[1]*cj[1] + cj[2]*cj[2] + cj[3]*cj[3];
    #pragma unroll
    for (int m = 32; m >= 1; m >>= 1) { s1 += __shfl_xor(s1, m); s2 += __shfl_xor(s2, m); }
    __syncthreads();
    if (lane == 0) { red[wid][0] = s1; red[wid][1] = s2; }
    __syncthreads();
    const float S1 = red[0][0] + red[1][0] + red[2][0] + red[3][0];
    const float S2 = red[0][1] + red[1][1] + red[2][1] + red[3][1];
    const float mu = S1 * (1.f / 1024.f);
    const float var = S2 * (1.f / 1024.f) - mu * mu;
    const float rstd = rsqrtf(var + 1e-5f);
    float4 g4 = *(const float4*)(gamma + k0i);
    float4 b4 = *(const float4*)(beta + k0i);
    float4 res;
    res.x = (cj[0] - mu) * rstd * g4.x + b4.x;
    res.y = (cj[1] - mu) * rstd * g4.y + b4.y;
    res.z = (cj[2] - mu) * rstd * g4.z + b4.z;
    res.w = (cj[3] - mu) * rstd * g4.w + b4.w;
    *(float4*)(out + (size_t)row * 1024 + k0i) = res;
}

extern "C" void kernel_launch(void* const* d_in, const int* in_sizes, int n_in,
                              void* d_out, int out_size, void* d_ws, size_t ws_size,
                              hipStream_t stream)
{
    if (ws_size < WS_NEED) {
        fprintf(stderr, "kernel_launch: ws_size %zu < required %llu\n",
                ws_size, (unsigned long long)WS_NEED);
        return;
    }
    const float* hid = (const float*)d_in[0];
    const float* Wp  = (const float*)d_in[1];
    const float* bp  = (const float*)d_in[2];
    const float* Wop = (const float*)d_in[3];
    const float* bop = (const float*)d_in[4];
    const float* Wtl = (const float*)d_in[5];
    const float* btl = (const float*)d_in[6];
    const float* gam = (const float*)d_in[7];
    const float* bet = (const float*)d_in[8];
    float* out = (float*)d_out;
    char* ws = (char*)d_ws;
    unsigned short* Abf  = (unsigned short*)(ws + WS_ABF);
    unsigned short* Wbf  = (unsigned short*)(ws + WS_WBF);
    unsigned short* proj = (unsigned short*)(ws + WS_PROJ);
    float4* op4 = (float4*)(ws + WS_OP4);
    float* wbuf = (float*)(ws + WS_WPTR);
    float* pbuf = (float*)(ws + WS_PPTR);

    k0<<<9216, 256, 0, stream>>>(hid, Wp, Wop, bop, Abf, Wbf, op4);
    k1<<<4112, 256, 0, stream>>>(Abf, Wbf, bp, proj, op4, wbuf, pbuf, out);
    k4<<<64,   256, 0, stream>>>(proj, wbuf, pbuf, out);
    k5<<<32768, 256, 0, stream>>>(proj, hid, Wtl, btl, gam, bet, out);
}

// Round 2
// 739.500 us; speedup vs baseline: 1.3231x; 1.3231x over previous
//
#include <hip/hip_runtime.h>
#include <hip/hip_bf16.h>
#include <cstdint>
#include <cstdio>

// B=16, S=2048, H=1024, D=16, T=5;  M = B*S = 32768, N = 2H = 2048, K = 1024.

typedef float f32x4 __attribute__((ext_vector_type(4)));
typedef __bf16 bf8v __attribute__((ext_vector_type(8)));

// d_ws byte offsets
#define WS_ABF   0ULL                 // 32768*1024*2  = 67,108,864  (hidden bf16; later reused as bf16 tops)
#define WS_WBF   67108864ULL          // 2048*1024*2   = 4,194,304   (W_proj bf16)
#define WS_PROJ  71303168ULL          // 32768*2048*2  = 134,217,728 (proj = [h_all|v_all] bf16)
#define WS_OP4   205520896ULL         // 32768*16      = 524,288     (op_probs padded float4)
#define WS_WP    206045184ULL         // 16*2048*16*2*4 = 4,194,304  (interleaved (w,p) f32)
#define WS_NEED  210239488ULL

// d_out float offsets
#define OUT_FINAL 0
#define OUT_STACK 33554432ULL         // (16,16,1024)
#define OUT_PTR   33816576ULL         // (16,16)
#define OUT_TOOLW 33816832ULL         // (16,2048,5)

__device__ __forceinline__ float bf2f(unsigned short u) {
    union { unsigned int i; float f; } v; v.i = ((unsigned int)u) << 16; return v.f;
}
__device__ __forceinline__ unsigned short f2bf(float f) {
    __hip_bfloat16 h = __float2bfloat16(f);
    return __builtin_bit_cast(unsigned short, h);
}
template<int C>
__device__ __forceinline__ float fdpp(float x) {
    return __int_as_float(__builtin_amdgcn_mov_dpp(__float_as_int(x), C, 0xF, 0xF, true));
}
__device__ __forceinline__ void gload_lds16(const void* g, void* l) {
    __builtin_amdgcn_global_load_lds(
        (__attribute__((address_space(1))) void*)(uintptr_t)g,
        (__attribute__((address_space(3))) void*)l,
        16, 0, 0);
}

// ---------------------------------------------------------------------------
// k0: hidden -> bf16 (A), W_proj -> bf16 (B), op_probs (f32).
// ---------------------------------------------------------------------------
__global__ __launch_bounds__(256) void k0(const float* __restrict__ hid,
                                          const float* __restrict__ Wp,
                                          const float* __restrict__ Wop,
                                          const float* __restrict__ bop,
                                          unsigned short* __restrict__ Abf,
                                          unsigned short* __restrict__ Wbf,
                                          float4* __restrict__ op4)
{
    const int bid = blockIdx.x, tid = threadIdx.x;
    if (bid < 8192) {
        const int wid = tid >> 6, lane = tid & 63;
        const int row = bid * 4 + wid;
        const float* hrow = hid + (size_t)row * 1024 + lane * 16;
        float xs[16];
        #pragma unroll
        for (int j = 0; j < 4; ++j) {
            float4 t = *(const float4*)(hrow + j * 4);
            xs[j*4+0] = t.x; xs[j*4+1] = t.y; xs[j*4+2] = t.z; xs[j*4+3] = t.w;
        }
        unsigned short us[16];
        #pragma unroll
        for (int j = 0; j < 16; ++j) us[j] = f2bf(xs[j]);
        uint4 ulo, uhi;
        ulo.x = (unsigned)us[0]  | ((unsigned)us[1]  << 16);
        ulo.y = (unsigned)us[2]  | ((unsigned)us[3]  << 16);
        ulo.z = (unsigned)us[4]  | ((unsigned)us[5]  << 16);
        ulo.w = (unsigned)us[6]  | ((unsigned)us[7]  << 16);
        uhi.x = (unsigned)us[8]  | ((unsigned)us[9]  << 16);
        uhi.y = (unsigned)us[10] | ((unsigned)us[11] << 16);
        uhi.z = (unsigned)us[12] | ((unsigned)us[13] << 16);
        uhi.w = (unsigned)us[14] | ((unsigned)us[15] << 16);
        unsigned short* arow = Abf + (size_t)row * 1024 + lane * 16;
        *(uint4*)(arow)     = ulo;
        *(uint4*)(arow + 8) = uhi;
        float pt[3] = {0.f, 0.f, 0.f};
        #pragma unroll
        for (int o = 0; o < 3; ++o) {
            const float* wrow = Wop + o * 1024 + lane * 16;
            #pragma unroll
            for (int j = 0; j < 4; ++j) {
                float4 t = *(const float4*)(wrow + j * 4);
                pt[o] += xs[j*4+0]*t.x + xs[j*4+1]*t.y + xs[j*4+2]*t.z + xs[j*4+3]*t.w;
            }
        }
        #pragma unroll
        for (int o = 0; o < 3; ++o)
            #pragma unroll
            for (int m = 32; m >= 1; m >>= 1) pt[o] += __shfl_xor(pt[o], m);
        if (lane == 0) {
            float l0 = pt[0] + bop[0], l1 = pt[1] + bop[1], l2 = pt[2] + bop[2];
            float mx = fmaxf(l0, fmaxf(l1, l2));
            float e0 = expf(l0 - mx), e1 = expf(l1 - mx), e2 = expf(l2 - mx);
            float inv = 1.0f / (e0 + e1 + e2);
            float4 r; r.x = e0 * inv; r.y = e1 * inv; r.z = e2 * inv; r.w = 0.f;
            op4[row] = r;
        }
    } else {
        const int b2 = bid - 8192;
        const size_t base = (size_t)b2 * 2048 + tid * 8;
        float4 a = *(const float4*)(Wp + base);
        float4 b = *(const float4*)(Wp + base + 4);
        unsigned short vs[8] = { f2bf(a.x), f2bf(a.y), f2bf(a.z), f2bf(a.w),
                                 f2bf(b.x), f2bf(b.y), f2bf(b.z), f2bf(b.w) };
        uint4 u;
        u.x = (unsigned)vs[0] | ((unsigned)vs[1] << 16);
        u.y = (unsigned)vs[2] | ((unsigned)vs[3] << 16);
        u.z = (unsigned)vs[4] | ((unsigned)vs[5] << 16);
        u.w = (unsigned)vs[6] | ((unsigned)vs[7] << 16);
        *(uint4*)(Wbf + base) = u;
    }
}

// ---------------------------------------------------------------------------
// k1: blocks 0..15 pointer scan (DPP over 16 lanes, float2 (w,p) stores);
//     blocks 16..4111 bf16 MFMA GEMM 128x128, BK=64, (row&7)<<4 swizzle,
//     global_load_lds width-16, XCD-aware block swizzle.
// ---------------------------------------------------------------------------
__global__ __launch_bounds__(256) void k1(const unsigned short* __restrict__ Abf,
                                          const unsigned short* __restrict__ Wbf,
                                          const float* __restrict__ bproj,
                                          unsigned short* __restrict__ proj,
                                          const float4* __restrict__ op4,
                                          float* __restrict__ wpbuf,
                                          float* __restrict__ out)
{
    __shared__ uint4 sm[2048];   // 32 KiB
    const int bid = blockIdx.x, tid = threadIdx.x;

    if (bid < 16) {
        const int b = bid;
        #pragma unroll
        for (int i = 0; i < 8; ++i)
            sm[tid + i * 256] = ((const uint4*)op4)[(size_t)b * 2048 + tid + i * 256];
        __syncthreads();
        if (tid >= 64) return;               // wave 0 only from here
        __builtin_amdgcn_s_setprio(1);
        const int lane = tid, d = lane & 15;
        const float probe = (float)d;
        const bool ror1_is_push = (fdpp<0x121>(probe) == (float)((d + 15) & 15));
        float p = (d == 0) ? 1.0f : 0.0f;
        const float4* smf = (const float4*)sm;
        float4 o0 = smf[0], o1 = smf[1];
        float* wpb = wpbuf + (size_t)b * 2048 * 32;
        #pragma unroll 2
        for (int s = 0; s < 2048; ++s) {
            float4 o2 = smf[(s + 2 < 2048) ? (s + 2) : 2047];
            const float push = o0.x, pop = o0.y, nop = o0.z;
            const float ra = fdpp<0x121>(p);
            const float rb = fdpp<0x12F>(p);
            const float ppush = ror1_is_push ? ra : rb;   // p[d-1]
            const float ppop  = ror1_is_push ? rb : ra;   // p[d+1]
            const float w = push * ppush;
            float lin = push * ppush + pop * ppop + nop * p;
            float x2 = lin * lin;
            float x5 = x2 * x2 * lin;
            float sum = x5;
            sum += fdpp<0x128>(sum);
            sum += fdpp<0x124>(sum);
            sum += fdpp<0x122>(sum);
            sum += fdpp<0x121>(sum);
            float pn = x5 * __builtin_amdgcn_rcpf(sum + 1e-8f);
            if (lane < 16) {
                float2 wp; wp.x = w; wp.y = pn;
                *(float2*)(wpb + ((size_t)s * 16 + d) * 2) = wp;
            }
            p = pn;
            o0 = o1; o1 = o2;
        }
        if (lane < 16) out[OUT_PTR + (size_t)b * 16 + d] = p;
        return;
    }

    // ---- GEMM: proj[m,n] = sum_k A[m,k]*W[n,k] + b_proj[n] ----
    int bid2 = bid - 16;
    bid2 = (bid2 & 7) * 512 + (bid2 >> 3);     // XCD-contiguous (4096 % 8 == 0)
    const int gm = bid2 & 255;
    const int gn = bid2 >> 8;
    const int wid = tid >> 6, lane = tid & 63;
    const int wm = wid & 1, wn = wid >> 1;
    const size_t row0 = (size_t)gm * 128;
    const size_t col0 = (size_t)gn * 128;
    char* smc = (char*)sm;
    const char* Ab = (const char*)Abf;
    const char* Bb = (const char*)Wbf;
    f32x4 acc[4][4];
    const f32x4 z = {0.f, 0.f, 0.f, 0.f};
    #pragma unroll
    for (int i = 0; i < 4; ++i)
        #pragma unroll
        for (int j = 0; j < 4; ++j) acc[i][j] = z;

    for (int kt = 0; kt < 16; ++kt) {
        // swz(x) = x ^ ((x>>7 & 7) << 4); linear LDS dest, swizzled global source
        #pragma unroll
        for (int i = 0; i < 4; ++i) {
            const int off  = (i * 256 + tid) * 16;
            const int soff = off ^ (((off >> 7) & 7) << 4);
            gload_lds16(Ab + (row0 + (size_t)(soff >> 7)) * 2048 + (size_t)kt * 128 + (soff & 127),
                        smc + (i * 256 + wid * 64) * 16);
        }
        #pragma unroll
        for (int i = 0; i < 4; ++i) {
            const int off  = (i * 256 + tid) * 16;
            const int soff = off ^ (((off >> 7) & 7) << 4);
            gload_lds16(Bb + (col0 + (size_t)(soff >> 7)) * 2048 + (size_t)kt * 128 + (soff & 127),
                        smc + 16384 + (i * 256 + wid * 64) * 16);
        }
        __syncthreads();
        bf8v af[4][2], bfv[4][2];
        #pragma unroll
        for (int mr = 0; mr < 4; ++mr)
            #pragma unroll
            for (int kk = 0; kk < 2; ++kk) {
                int byt = (wm * 64 + mr * 16 + (lane & 15)) * 128 + kk * 64 + ((lane >> 4) * 16);
                byt ^= ((byt >> 7) & 7) << 4;
                af[mr][kk] = *(const bf8v*)(smc + byt);
            }
        #pragma unroll
        for (int nr = 0; nr < 4; ++nr)
            #pragma unroll
            for (int kk = 0; kk < 2; ++kk) {
                int byt = (wn * 64 + nr * 16 + (lane & 15)) * 128 + kk * 64 + ((lane >> 4) * 16);
                byt ^= ((byt >> 7) & 7) << 4;
                bfv[nr][kk] = *(const bf8v*)(smc + 16384 + byt);
            }
        #pragma unroll
        for (int mr = 0; mr < 4; ++mr)
            #pragma unroll
            for (int nr = 0; nr < 4; ++nr) {
                acc[mr][nr] = __builtin_amdgcn_mfma_f32_16x16x32_bf16(af[mr][0], bfv[nr][0], acc[mr][nr], 0, 0, 0);
                acc[mr][nr] = __builtin_amdgcn_mfma_f32_16x16x32_bf16(af[mr][1], bfv[nr][1], acc[mr][nr], 0, 0, 0);
            }
        __syncthreads();
    }
    #pragma unroll
    for (int mr = 0; mr < 4; ++mr) {
        const int rloc = wm * 64 + mr * 16 + ((lane >> 4) * 4);
        #pragma unroll
        for (int nr = 0; nr < 4; ++nr) {
            const size_t col = col0 + wn * 64 + nr * 16 + (lane & 15);
            const float bias = bproj[col];
            #pragma unroll
            for (int j = 0; j < 4; ++j)
                proj[(row0 + rloc + j) * 2048 + col] = f2bf(acc[mr][nr][j] + bias);
        }
    }
}

// ---------------------------------------------------------------------------
// k4: stack scan, D split 4-ways. 256 blocks = 16 b x 16 h-chunks of 64.
//     4 waves/block; thread owns 4 stack slots for one h. v and (w,p) double-
//     buffered in LDS via global_load_lds. tops (bf16) overwrite Abf region.
// ---------------------------------------------------------------------------
__global__ __launch_bounds__(256) void k4(const unsigned short* __restrict__ proj,
                                          const float* __restrict__ wpbuf,
                                          unsigned short* __restrict__ tops,
                                          float* __restrict__ out)
{
    __shared__ unsigned short vlds[2][4096];  // 2 x 64 steps x 64 h bf16 = 16 KiB
    __shared__ float wplds[2][2048];          // 2 x 64 steps x 16 d x (w,p) = 16 KiB
    const int bid = blockIdx.x, tid = threadIdx.x;
    const int wid = tid >> 6, lane = tid & 63;
    const int dg = lane >> 4;                 // d-group: slots dg*4 .. dg*4+3
    const int hl = wid * 16 + (lane & 15);    // h within chunk
    const int b = bid >> 4, hb = (bid & 15) * 64;
    const char* vsrc = (const char*)proj + ((size_t)b * 2048 * 2048 + 1024 + hb) * 2;
    const char* wpsrc = (const char*)(wpbuf + (size_t)b * 2048 * 32);
    unsigned short* topw = tops + (size_t)b * 2048 * 1024 + hb + hl;

    float st0 = 0.f, st1 = 0.f, st2 = 0.f, st3 = 0.f;

    auto STAGE = [&](int c, int buf) {
        #pragma unroll
        for (int i = 0; i < 2; ++i) {
            const int g = i * 256 + tid;
            gload_lds16(vsrc + (size_t)(c * 64 + (g >> 3)) * 4096 + (g & 7) * 16,
                        (char*)vlds + buf * 8192 + i * 4096 + wid * 1024);
        }
        #pragma unroll
        for (int i = 0; i < 2; ++i) {
            gload_lds16(wpsrc + (size_t)c * 8192 + i * 4096 + tid * 16,
                        (char*)wplds + buf * 8192 + i * 4096 + wid * 1024);
        }
    };

    STAGE(0, 0);
    __syncthreads();
    for (int c = 0; c < 32; ++c) {
        const int cur = c & 1;
        if (c + 1 < 32) STAGE(c + 1, cur ^ 1);
        const unsigned short* vl = vlds[cur];
        const float* wl = wplds[cur];
        #pragma unroll 4
        for (int r = 0; r < 64; ++r) {
            const float v = bf2f(vl[r * 64 + hl]);
            float4 lo = *(const float4*)(wl + r * 32 + dg * 8);      // w[d0],p[d0],w[d0+1],p[d0+1]
            float4 hi = *(const float4*)(wl + r * 32 + dg * 8 + 4);  // w[d0+2],p[d0+2],...
            st0 = fmaf(lo.x, v - st0, st0);
            st1 = fmaf(lo.z, v - st1, st1);
            st2 = fmaf(hi.x, v - st2, st2);
            st3 = fmaf(hi.z, v - st3, st3);
            float t = lo.y * st0 + lo.w * st1 + hi.y * st2 + hi.w * st3;
            t += __shfl_xor(t, 16);
            t += __shfl_xor(t, 32);
            if (dg == 0) topw[(size_t)(c * 64 + r) * 1024] = f2bf(t);
        }
        __syncthreads();   // drains vmcnt(0): next buffer staged, this buffer free
    }
    const int h = hb + hl;
    out[OUT_STACK + ((size_t)b * 16 + dg * 4 + 0) * 1024 + h] = st0;
    out[OUT_STACK + ((size_t)b * 16 + dg * 4 + 1) * 1024 + h] = st1;
    out[OUT_STACK + ((size_t)b * 16 + dg * 4 + 2) * 1024 + h] = st2;
    out[OUT_STACK + ((size_t)b * 16 + dg * 4 + 3) * 1024 + h] = st3;
}

// ---------------------------------------------------------------------------
// k5: epilogue per (b,s) row: tool softmax, apply tools, residual, LayerNorm.
// ---------------------------------------------------------------------------
__global__ __launch_bounds__(256) void k5(const unsigned short* __restrict__ proj,
                                          const unsigned short* __restrict__ tops,
                                          const float* __restrict__ hid,
                                          const float* __restrict__ Wtool,
                                          const float* __restrict__ btool,
                                          const float* __restrict__ gamma,
                                          const float* __restrict__ beta,
                                          float* __restrict__ out)
{
    __shared__ float red[4][8];
    const int row = blockIdx.x, tid = threadIdx.x;
    const int wid = tid >> 6, lane = tid & 63;
    const int k0i = tid * 4;
    uint2 hu = *(const uint2*)(proj + (size_t)row * 2048 + k0i);
    float hh[4];
    hh[0] = bf2f(hu.x & 0xffff); hh[1] = bf2f(hu.x >> 16);
    hh[2] = bf2f(hu.y & 0xffff); hh[3] = bf2f(hu.y >> 16);
    uint2 tu = *(const uint2*)(tops + (size_t)row * 1024 + k0i);
    float xs[4];
    xs[0] = bf2f(tu.x & 0xffff); xs[1] = bf2f(tu.x >> 16);
    xs[2] = bf2f(tu.y & 0xffff); xs[3] = bf2f(tu.y >> 16);
    float4 hd4 = *(const float4*)(hid + (size_t)row * 1024 + k0i);
    float hds[4] = {hd4.x, hd4.y, hd4.z, hd4.w};
    float pt[5];
    #pragma unroll
    for (int t = 0; t < 5; ++t) {
        float4 wv = *(const float4*)(Wtool + t * 1024 + k0i);
        pt[t] = hh[0]*wv.x + hh[1]*wv.y + hh[2]*wv.z + hh[3]*wv.w;
    }
    #pragma unroll
    for (int t = 0; t < 5; ++t)
        #pragma unroll
        for (int m = 32; m >= 1; m >>= 1) pt[t] += __shfl_xor(pt[t], m);
    if (lane == 0) {
        #pragma unroll
        for (int t = 0; t < 5; ++t) red[wid][t] = pt[t];
    }
    __syncthreads();
    float tw[5];
    {
        float lg[5];
        #pragma unroll
        for (int t = 0; t < 5; ++t)
            lg[t] = red[0][t] + red[1][t] + red[2][t] + red[3][t] + btool[t];
        float mx = fmaxf(fmaxf(fmaxf(lg[0], lg[1]), fmaxf(lg[2], lg[3])), lg[4]);
        float se = 0.f;
        #pragma unroll
        for (int t = 0; t < 5; ++t) { tw[t] = expf(lg[t] - mx); se += tw[t]; }
        float inv = 1.0f / se;
        #pragma unroll
        for (int t = 0; t < 5; ++t) tw[t] *= inv;
    }
    if (tid < 5) out[OUT_TOOLW + (size_t)row * 5 + tid] = tw[tid];
    float cj[4];
    #pragma unroll
    for (int j = 0; j < 4; ++j) {
        const float x = xs[j];
        const float rl = fmaxf(x, 0.f);
        const float gl = 0.5f * x * (1.f + erff(x * 0.70710678118654752f));
        const float th = tanhf(x);
        const float sg = 1.f / (1.f + expf(-x));
        const float pr = rl*tw[0] + gl*tw[1] + th*tw[2] + sg*tw[3] + x*tw[4];
        cj[j] = hh[j] + pr + hds[j];
    }
    float s1 = cj[0] + cj[1] + cj[2] + cj[3];
    float s2 = cj[0]*cj[0] + cj[1]*cj[1] + cj[2]*cj[2] + cj[3]*cj[3];
    #pragma unroll
    for (int m = 32; m >= 1; m >>= 1) { s1 += __shfl_xor(s1, m); s2 += __shfl_xor(s2, m); }
    __syncthreads();
    if (lane == 0) { red[wid][0] = s1; red[wid][1] = s2; }
    __syncthreads();
    const float S1 = red[0][0] + red[1][0] + red[2][0] + red[3][0];
    const float S2 = red[0][1] + red[1][1] + red[2][1] + red[3][1];
    const float mu = S1 * (1.f / 1024.f);
    const float var = S2 * (1.f / 1024.f) - mu * mu;
    const float rstd = rsqrtf(var + 1e-5f);
    float4 g4 = *(const float4*)(gamma + k0i);
    float4 b4 = *(const float4*)(beta + k0i);
    float4 res;
    res.x = (cj[0] - mu) * rstd * g4.x + b4.x;
    res.y = (cj[1] - mu) * rstd * g4.y + b4.y;
    res.z = (cj[2] - mu) * rstd * g4.z + b4.z;
    res.w = (cj[3] - mu) * rstd * g4.w + b4.w;
    *(float4*)(out + (size_t)row * 1024 + k0i) = res;
}

extern "C" void kernel_launch(void* const* d_in, const int* in_sizes, int n_in,
                              void* d_out, int out_size, void* d_ws, size_t ws_size,
                              hipStream_t stream)
{
    if (ws_size < WS_NEED) {
        fprintf(stderr, "kernel_launch: ws_size %zu < required %llu\n",
                ws_size, (unsigned long long)WS_NEED);
        return;
    }
    const float* hid = (const float*)d_in[0];
    const float* Wp  = (const float*)d_in[1];
    const float* bp  = (const float*)d_in[2];
    const float* Wop = (const float*)d_in[3];
    const float* bop = (const float*)d_in[4];
    const float* Wtl = (const float*)d_in[5];
    const float* btl = (const float*)d_in[6];
    const float* gam = (const float*)d_in[7];
    const float* bet = (const float*)d_in[8];
    float* out = (float*)d_out;
    char* ws = (char*)d_ws;
    unsigned short* Abf  = (unsigned short*)(ws + WS_ABF);   // hidden bf16, then tops bf16
    unsigned short* Wbf  = (unsigned short*)(ws + WS_WBF);
    unsigned short* proj = (unsigned short*)(ws + WS_PROJ);
    float4* op4 = (float4*)(ws + WS_OP4);
    float* wpbuf = (float*)(ws + WS_WP);

    k0<<<9216, 256, 0, stream>>>(hid, Wp, Wop, bop, Abf, Wbf, op4);
    k1<<<4112, 256, 0, stream>>>(Abf, Wbf, bp, proj, op4, wpbuf, out);
    k4<<<256,  256, 0, stream>>>(proj, wpbuf, Abf, out);
    k5<<<32768, 256, 0, stream>>>(proj, Abf, hid, Wtl, btl, gam, bet, out);
}

// Round 3
// 640.505 us; speedup vs baseline: 1.5276x; 1.1546x over previous
//
#include <hip/hip_runtime.h>
#include <hip/hip_bf16.h>
#include <cstdint>
#include <cstdio>

// B=16, S=2048, H=1024, D=16, T=5;  M = B*S = 32768, N = 2H = 2048, K = 1024.

typedef float f32x4 __attribute__((ext_vector_type(4)));
typedef __bf16 bf8v __attribute__((ext_vector_type(8)));

// d_ws byte offsets
#define WS_ABF   0ULL                 // 32768*1024*2  = 67,108,864  (hidden bf16; later reused as bf16 tops)
#define WS_WBF   67108864ULL          // 2048*1024*2   = 4,194,304   (W_proj bf16)
#define WS_PROJ  71303168ULL          // 32768*2048*2  = 134,217,728 (proj = [h_all|v_all] bf16)
#define WS_OP4   205520896ULL         // 32768*16      = 524,288     (op_probs padded float4)
#define WS_WP    206045184ULL         // 16*2048*16*2*4 = 4,194,304  (interleaved (w,p) f32)
#define WS_NEED  210239488ULL

// d_out float offsets
#define OUT_FINAL 0
#define OUT_STACK 33554432ULL         // (16,16,1024)
#define OUT_PTR   33816576ULL         // (16,16)
#define OUT_TOOLW 33816832ULL         // (16,2048,5)

__device__ __forceinline__ float bf2f(unsigned short u) {
    union { unsigned int i; float f; } v; v.i = ((unsigned int)u) << 16; return v.f;
}
__device__ __forceinline__ unsigned short f2bf(float f) {
    __hip_bfloat16 h = __float2bfloat16(f);
    return __builtin_bit_cast(unsigned short, h);
}
template<int C>
__device__ __forceinline__ float fdpp(float x) {
    return __int_as_float(__builtin_amdgcn_mov_dpp(__float_as_int(x), C, 0xF, 0xF, true));
}
__device__ __forceinline__ void gload_lds16(const void* g, void* l) {
    __builtin_amdgcn_global_load_lds(
        (__attribute__((address_space(1))) void*)(uintptr_t)g,
        (__attribute__((address_space(3))) void*)l,
        16, 0, 0);
}

// ---------------------------------------------------------------------------
// k0: hidden -> bf16 (A), W_proj -> bf16 (B), op_probs (f32).
// ---------------------------------------------------------------------------
__global__ __launch_bounds__(256) void k0(const float* __restrict__ hid,
                                          const float* __restrict__ Wp,
                                          const float* __restrict__ Wop,
                                          const float* __restrict__ bop,
                                          unsigned short* __restrict__ Abf,
                                          unsigned short* __restrict__ Wbf,
                                          float4* __restrict__ op4)
{
    const int bid = blockIdx.x, tid = threadIdx.x;
    if (bid < 8192) {
        const int wid = tid >> 6, lane = tid & 63;
        const int row = bid * 4 + wid;
        const float* hrow = hid + (size_t)row * 1024 + lane * 16;
        float xs[16];
        #pragma unroll
        for (int j = 0; j < 4; ++j) {
            float4 t = *(const float4*)(hrow + j * 4);
            xs[j*4+0] = t.x; xs[j*4+1] = t.y; xs[j*4+2] = t.z; xs[j*4+3] = t.w;
        }
        unsigned short us[16];
        #pragma unroll
        for (int j = 0; j < 16; ++j) us[j] = f2bf(xs[j]);
        uint4 ulo, uhi;
        ulo.x = (unsigned)us[0]  | ((unsigned)us[1]  << 16);
        ulo.y = (unsigned)us[2]  | ((unsigned)us[3]  << 16);
        ulo.z = (unsigned)us[4]  | ((unsigned)us[5]  << 16);
        ulo.w = (unsigned)us[6]  | ((unsigned)us[7]  << 16);
        uhi.x = (unsigned)us[8]  | ((unsigned)us[9]  << 16);
        uhi.y = (unsigned)us[10] | ((unsigned)us[11] << 16);
        uhi.z = (unsigned)us[12] | ((unsigned)us[13] << 16);
        uhi.w = (unsigned)us[14] | ((unsigned)us[15] << 16);
        unsigned short* arow = Abf + (size_t)row * 1024 + lane * 16;
        *(uint4*)(arow)     = ulo;
        *(uint4*)(arow + 8) = uhi;
        float pt[3] = {0.f, 0.f, 0.f};
        #pragma unroll
        for (int o = 0; o < 3; ++o) {
            const float* wrow = Wop + o * 1024 + lane * 16;
            #pragma unroll
            for (int j = 0; j < 4; ++j) {
                float4 t = *(const float4*)(wrow + j * 4);
                pt[o] += xs[j*4+0]*t.x + xs[j*4+1]*t.y + xs[j*4+2]*t.z + xs[j*4+3]*t.w;
            }
        }
        #pragma unroll
        for (int o = 0; o < 3; ++o)
            #pragma unroll
            for (int m = 32; m >= 1; m >>= 1) pt[o] += __shfl_xor(pt[o], m);
        if (lane == 0) {
            float l0 = pt[0] + bop[0], l1 = pt[1] + bop[1], l2 = pt[2] + bop[2];
            float mx = fmaxf(l0, fmaxf(l1, l2));
            float e0 = expf(l0 - mx), e1 = expf(l1 - mx), e2 = expf(l2 - mx);
            float inv = 1.0f / (e0 + e1 + e2);
            float4 r; r.x = e0 * inv; r.y = e1 * inv; r.z = e2 * inv; r.w = 0.f;
            op4[row] = r;
        }
    } else {
        const int b2 = bid - 8192;
        const size_t base = (size_t)b2 * 2048 + tid * 8;
        float4 a = *(const float4*)(Wp + base);
        float4 b = *(const float4*)(Wp + base + 4);
        unsigned short vs[8] = { f2bf(a.x), f2bf(a.y), f2bf(a.z), f2bf(a.w),
                                 f2bf(b.x), f2bf(b.y), f2bf(b.z), f2bf(b.w) };
        uint4 u;
        u.x = (unsigned)vs[0] | ((unsigned)vs[1] << 16);
        u.y = (unsigned)vs[2] | ((unsigned)vs[3] << 16);
        u.z = (unsigned)vs[4] | ((unsigned)vs[5] << 16);
        u.w = (unsigned)vs[6] | ((unsigned)vs[7] << 16);
        *(uint4*)(Wbf + base) = u;
    }
}

// ---------------------------------------------------------------------------
// k1: blocks 0..15 pointer scan (DPP over 16 lanes, float2 (w,p) stores);
//     blocks 16..4111 bf16 MFMA GEMM 128x128, BK=64, (row&7)<<4 swizzle,
//     global_load_lds width-16, XCD-aware block swizzle.
// ---------------------------------------------------------------------------
__global__ __launch_bounds__(256) void k1(const unsigned short* __restrict__ Abf,
                                          const unsigned short* __restrict__ Wbf,
                                          const float* __restrict__ bproj,
                                          unsigned short* __restrict__ proj,
                                          const float4* __restrict__ op4,
                                          float* __restrict__ wpbuf,
                                          float* __restrict__ out)
{
    __shared__ uint4 sm[2048];   // 32 KiB
    const int bid = blockIdx.x, tid = threadIdx.x;

    if (bid < 16) {
        const int b = bid;
        #pragma unroll
        for (int i = 0; i < 8; ++i)
            sm[tid + i * 256] = ((const uint4*)op4)[(size_t)b * 2048 + tid + i * 256];
        __syncthreads();
        if (tid >= 64) return;               // wave 0 only from here
        __builtin_amdgcn_s_setprio(1);
        const int lane = tid, d = lane & 15;
        const float probe = (float)d;
        const bool ror1_is_push = (fdpp<0x121>(probe) == (float)((d + 15) & 15));
        float p = (d == 0) ? 1.0f : 0.0f;
        const float4* smf = (const float4*)sm;
        float4 o0 = smf[0], o1 = smf[1];
        float* wpb = wpbuf + (size_t)b * 2048 * 32;
        #pragma unroll 2
        for (int s = 0; s < 2048; ++s) {
            float4 o2 = smf[(s + 2 < 2048) ? (s + 2) : 2047];
            const float push = o0.x, pop = o0.y, nop = o0.z;
            const float ra = fdpp<0x121>(p);
            const float rb = fdpp<0x12F>(p);
            const float ppush = ror1_is_push ? ra : rb;   // p[d-1]
            const float ppop  = ror1_is_push ? rb : ra;   // p[d+1]
            const float w = push * ppush;
            float lin = push * ppush + pop * ppop + nop * p;
            float x2 = lin * lin;
            float x5 = x2 * x2 * lin;
            float sum = x5;
            sum += fdpp<0x128>(sum);
            sum += fdpp<0x124>(sum);
            sum += fdpp<0x122>(sum);
            sum += fdpp<0x121>(sum);
            float pn = x5 * __builtin_amdgcn_rcpf(sum + 1e-8f);
            if (lane < 16) {
                float2 wp; wp.x = w; wp.y = pn;
                *(float2*)(wpb + ((size_t)s * 16 + d) * 2) = wp;
            }
            p = pn;
            o0 = o1; o1 = o2;
        }
        if (lane < 16) out[OUT_PTR + (size_t)b * 16 + d] = p;
        return;
    }

    // ---- GEMM: proj[m,n] = sum_k A[m,k]*W[n,k] + b_proj[n] ----
    int bid2 = bid - 16;
    bid2 = (bid2 & 7) * 512 + (bid2 >> 3);     // XCD-contiguous (4096 % 8 == 0)
    const int gm = bid2 & 255;
    const int gn = bid2 >> 8;
    const int wid = tid >> 6, lane = tid & 63;
    const int wm = wid & 1, wn = wid >> 1;
    const size_t row0 = (size_t)gm * 128;
    const size_t col0 = (size_t)gn * 128;
    char* smc = (char*)sm;
    const char* Ab = (const char*)Abf;
    const char* Bb = (const char*)Wbf;
    f32x4 acc[4][4];
    const f32x4 z = {0.f, 0.f, 0.f, 0.f};
    #pragma unroll
    for (int i = 0; i < 4; ++i)
        #pragma unroll
        for (int j = 0; j < 4; ++j) acc[i][j] = z;

    for (int kt = 0; kt < 16; ++kt) {
        // swz(x) = x ^ ((x>>7 & 7) << 4); linear LDS dest, swizzled global source
        #pragma unroll
        for (int i = 0; i < 4; ++i) {
            const int off  = (i * 256 + tid) * 16;
            const int soff = off ^ (((off >> 7) & 7) << 4);
            gload_lds16(Ab + (row0 + (size_t)(soff >> 7)) * 2048 + (size_t)kt * 128 + (soff & 127),
                        smc + (i * 256 + wid * 64) * 16);
        }
        #pragma unroll
        for (int i = 0; i < 4; ++i) {
            const int off  = (i * 256 + tid) * 16;
            const int soff = off ^ (((off >> 7) & 7) << 4);
            gload_lds16(Bb + (col0 + (size_t)(soff >> 7)) * 2048 + (size_t)kt * 128 + (soff & 127),
                        smc + 16384 + (i * 256 + wid * 64) * 16);
        }
        __syncthreads();
        bf8v af[4][2], bfv[4][2];
        #pragma unroll
        for (int mr = 0; mr < 4; ++mr)
            #pragma unroll
            for (int kk = 0; kk < 2; ++kk) {
                int byt = (wm * 64 + mr * 16 + (lane & 15)) * 128 + kk * 64 + ((lane >> 4) * 16);
                byt ^= ((byt >> 7) & 7) << 4;
                af[mr][kk] = *(const bf8v*)(smc + byt);
            }
        #pragma unroll
        for (int nr = 0; nr < 4; ++nr)
            #pragma unroll
            for (int kk = 0; kk < 2; ++kk) {
                int byt = (wn * 64 + nr * 16 + (lane & 15)) * 128 + kk * 64 + ((lane >> 4) * 16);
                byt ^= ((byt >> 7) & 7) << 4;
                bfv[nr][kk] = *(const bf8v*)(smc + 16384 + byt);
            }
        #pragma unroll
        for (int mr = 0; mr < 4; ++mr)
            #pragma unroll
            for (int nr = 0; nr < 4; ++nr) {
                acc[mr][nr] = __builtin_amdgcn_mfma_f32_16x16x32_bf16(af[mr][0], bfv[nr][0], acc[mr][nr], 0, 0, 0);
                acc[mr][nr] = __builtin_amdgcn_mfma_f32_16x16x32_bf16(af[mr][1], bfv[nr][1], acc[mr][nr], 0, 0, 0);
            }
        __syncthreads();
    }
    #pragma unroll
    for (int mr = 0; mr < 4; ++mr) {
        const int rloc = wm * 64 + mr * 16 + ((lane >> 4) * 4);
        #pragma unroll
        for (int nr = 0; nr < 4; ++nr) {
            const size_t col = col0 + wn * 64 + nr * 16 + (lane & 15);
            const float bias = bproj[col];
            #pragma unroll
            for (int j = 0; j < 4; ++j)
                proj[(row0 + rloc + j) * 2048 + col] = f2bf(acc[mr][nr][j] + bias);
        }
    }
}

// ---------------------------------------------------------------------------
// k4 v3: stack scan, D split 8-ways (2 slots/thread). 512 blocks = 16 b x 32
//     h-chunks of 32. Thread (h = tid&31, dg = tid>>5). Serial loop has NO
//     global ops and NO multi-hop shuffles: one permlane-pair combine + one
//     LDS partial write per step; tops produced by a per-chunk reduce pass.
//     v and (w,p) double-buffered via global_load_lds.
// ---------------------------------------------------------------------------
__global__ __launch_bounds__(256) void k4(const unsigned short* __restrict__ proj,
                                          const float* __restrict__ wpbuf,
                                          unsigned short* __restrict__ tops,
                                          float* __restrict__ out)
{
    __shared__ unsigned short vlds[2][1024];  // 2 x (32 s x 32 h) bf16 = 4 KiB
    __shared__ float wplds[2][1024];          // 2 x (32 s x 16 d x 2) f32 = 8 KiB
    __shared__ float part[32][4][32];         // 32 s x 4 dq x 32 h f32 = 16 KiB
    const int bid = blockIdx.x, tid = threadIdx.x;
    const int wid = tid >> 6, lane = tid & 63;
    const int h  = tid & 31;                  // h within chunk
    const int dg = tid >> 5;                  // 0..7 -> owns d = 2dg, 2dg+1
    const int b = bid >> 5, hb = (bid & 31) * 32;
    const char* vsrc  = (const char*)proj + ((size_t)b * 2048 * 2048 + 1024 + hb) * 2;
    const char* wpsrc = (const char*)(wpbuf + (size_t)b * 2048 * 32);
    unsigned short* topb = tops + (size_t)b * 2048 * 1024 + hb;

    float st0 = 0.f, st1 = 0.f;

    auto STAGE = [&](int c, int buf) {
        if (tid < 128)
            gload_lds16(vsrc + (size_t)(c * 32 + (tid >> 2)) * 4096 + (tid & 3) * 16,
                        (char*)vlds + buf * 2048 + wid * 1024);
        gload_lds16(wpsrc + (size_t)c * 4096 + tid * 16,
                    (char*)wplds + buf * 4096 + wid * 1024);
    };

    STAGE(0, 0);
    __syncthreads();
    for (int c = 0; c < 64; ++c) {
        const int cur = c & 1;
        if (c + 1 < 64) STAGE(c + 1, cur ^ 1);
        const unsigned short* vl = vlds[cur];
        const float* wl = wplds[cur];
        #pragma unroll 4
        for (int r = 0; r < 32; ++r) {
            const float v = bf2f(vl[r * 32 + h]);
            float4 f4 = *(const float4*)(wl + r * 32 + dg * 4);   // w0,p0,w1,p1
            st0 = fmaf(f4.x, v - st0, st0);
            st1 = fmaf(f4.z, v - st1, st1);
            float t = fmaf(f4.y, st0, f4.w * st1);
            t += __shfl_xor(t, 32);                                // combine dg pair
            if (lane < 32) part[r][wid][lane] = t;
        }
        __syncthreads();   // partials visible; also drains next chunk's staging
        #pragma unroll
        for (int j = 0; j < 4; ++j) {
            const int idx = j * 256 + tid;
            const int s = idx >> 5, hh = idx & 31;
            const float sum = (part[s][0][hh] + part[s][1][hh])
                            + (part[s][2][hh] + part[s][3][hh]);
            topb[(size_t)(c * 32 + s) * 1024 + hh] = f2bf(sum);
        }
        __syncthreads();   // protect partials from next chunk's writes
    }
    const int hg = hb + h;
    out[OUT_STACK + ((size_t)b * 16 + 2 * dg + 0) * 1024 + hg] = st0;
    out[OUT_STACK + ((size_t)b * 16 + 2 * dg + 1) * 1024 + hg] = st1;
}

// ---------------------------------------------------------------------------
// k5: epilogue per (b,s) row: tool softmax, apply tools, residual, LayerNorm.
// ---------------------------------------------------------------------------
__global__ __launch_bounds__(256) void k5(const unsigned short* __restrict__ proj,
                                          const unsigned short* __restrict__ tops,
                                          const float* __restrict__ hid,
                                          const float* __restrict__ Wtool,
                                          const float* __restrict__ btool,
                                          const float* __restrict__ gamma,
                                          const float* __restrict__ beta,
                                          float* __restrict__ out)
{
    __shared__ float red[4][8];
    const int row = blockIdx.x, tid = threadIdx.x;
    const int wid = tid >> 6, lane = tid & 63;
    const int k0i = tid * 4;
    uint2 hu = *(const uint2*)(proj + (size_t)row * 2048 + k0i);
    float hh[4];
    hh[0] = bf2f(hu.x & 0xffff); hh[1] = bf2f(hu.x >> 16);
    hh[2] = bf2f(hu.y & 0xffff); hh[3] = bf2f(hu.y >> 16);
    uint2 tu = *(const uint2*)(tops + (size_t)row * 1024 + k0i);
    float xs[4];
    xs[0] = bf2f(tu.x & 0xffff); xs[1] = bf2f(tu.x >> 16);
    xs[2] = bf2f(tu.y & 0xffff); xs[3] = bf2f(tu.y >> 16);
    float4 hd4 = *(const float4*)(hid + (size_t)row * 1024 + k0i);
    float hds[4] = {hd4.x, hd4.y, hd4.z, hd4.w};
    float pt[5];
    #pragma unroll
    for (int t = 0; t < 5; ++t) {
        float4 wv = *(const float4*)(Wtool + t * 1024 + k0i);
        pt[t] = hh[0]*wv.x + hh[1]*wv.y + hh[2]*wv.z + hh[3]*wv.w;
    }
    #pragma unroll
    for (int t = 0; t < 5; ++t)
        #pragma unroll
        for (int m = 32; m >= 1; m >>= 1) pt[t] += __shfl_xor(pt[t], m);
    if (lane == 0) {
        #pragma unroll
        for (int t = 0; t < 5; ++t) red[wid][t] = pt[t];
    }
    __syncthreads();
    float tw[5];
    {
        float lg[5];
        #pragma unroll
        for (int t = 0; t < 5; ++t)
            lg[t] = red[0][t] + red[1][t] + red[2][t] + red[3][t] + btool[t];
        float mx = fmaxf(fmaxf(fmaxf(lg[0], lg[1]), fmaxf(lg[2], lg[3])), lg[4]);
        float se = 0.f;
        #pragma unroll
        for (int t = 0; t < 5; ++t) { tw[t] = expf(lg[t] - mx); se += tw[t]; }
        float inv = 1.0f / se;
        #pragma unroll
        for (int t = 0; t < 5; ++t) tw[t] *= inv;
    }
    if (tid < 5) out[OUT_TOOLW + (size_t)row * 5 + tid] = tw[tid];
    float cj[4];
    #pragma unroll
    for (int j = 0; j < 4; ++j) {
        const float x = xs[j];
        const float rl = fmaxf(x, 0.f);
        const float gl = 0.5f * x * (1.f + erff(x * 0.70710678118654752f));
        const float th = tanhf(x);
        const float sg = 1.f / (1.f + expf(-x));
        const float pr = rl*tw[0] + gl*tw[1] + th*tw[2] + sg*tw[3] + x*tw[4];
        cj[j] = hh[j] + pr + hds[j];
    }
    float s1 = cj[0] + cj[1] + cj[2] + cj[3];
    float s2 = cj[0]*cj[0] + cj[1]*cj[1] + cj[2]*cj[2] + cj[3]*cj[3];
    #pragma unroll
    for (int m = 32; m >= 1; m >>= 1) { s1 += __shfl_xor(s1, m); s2 += __shfl_xor(s2, m); }
    __syncthreads();
    if (lane == 0) { red[wid][0] = s1; red[wid][1] = s2; }
    __syncthreads();
    const float S1 = red[0][0] + red[1][0] + red[2][0] + red[3][0];
    const float S2 = red[0][1] + red[1][1] + red[2][1] + red[3][1];
    const float mu = S1 * (1.f / 1024.f);
    const float var = S2 * (1.f / 1024.f) - mu * mu;
    const float rstd = rsqrtf(var + 1e-5f);
    float4 g4 = *(const float4*)(gamma + k0i);
    float4 b4 = *(const float4*)(beta + k0i);
    float4 res;
    res.x = (cj[0] - mu) * rstd * g4.x + b4.x;
    res.y = (cj[1] - mu) * rstd * g4.y + b4.y;
    res.z = (cj[2] - mu) * rstd * g4.z + b4.z;
    res.w = (cj[3] - mu) * rstd * g4.w + b4.w;
    *(float4*)(out + (size_t)row * 1024 + k0i) = res;
}

extern "C" void kernel_launch(void* const* d_in, const int* in_sizes, int n_in,
                              void* d_out, int out_size, void* d_ws, size_t ws_size,
                              hipStream_t stream)
{
    if (ws_size < WS_NEED) {
        fprintf(stderr, "kernel_launch: ws_size %zu < required %llu\n",
                ws_size, (unsigned long long)WS_NEED);
        return;
    }
    const float* hid = (const float*)d_in[0];
    const float* Wp  = (const float*)d_in[1];
    const float* bp  = (const float*)d_in[2];
    const float* Wop = (const float*)d_in[3];
    const float* bop = (const float*)d_in[4];
    const float* Wtl = (const float*)d_in[5];
    const float* btl = (const float*)d_in[6];
    const float* gam = (const float*)d_in[7];
    const float* bet = (const float*)d_in[8];
    float* out = (float*)d_out;
    char* ws = (char*)d_ws;
    unsigned short* Abf  = (unsigned short*)(ws + WS_ABF);   // hidden bf16, then tops bf16
    unsigned short* Wbf  = (unsigned short*)(ws + WS_WBF);
    unsigned short* proj = (unsigned short*)(ws + WS_PROJ);
    float4* op4 = (float4*)(ws + WS_OP4);
    float* wpbuf = (float*)(ws + WS_WP);

    k0<<<9216, 256, 0, stream>>>(hid, Wp, Wop, bop, Abf, Wbf, op4);
    k1<<<4112, 256, 0, stream>>>(Abf, Wbf, bp, proj, op4, wpbuf, out);
    k4<<<512,  256, 0, stream>>>(proj, wpbuf, Abf, out);
    k5<<<32768, 256, 0, stream>>>(proj, Abf, hid, Wtl, btl, gam, bet, out);
}

// Round 4
// 554.295 us; speedup vs baseline: 1.7652x; 1.1555x over previous
//
#include <hip/hip_runtime.h>
#include <hip/hip_bf16.h>
#include <cstdint>
#include <cstdio>

// B=16, S=2048, H=1024, D=16, T=5;  M = B*S = 32768, N = 2H = 2048, K = 1024.
// Stack scan decomposition: 32 chunks x 64 steps; affine composition
// st_end = Atot*st_start + st_local  (Atot = prod(1-w) over chunk).

typedef float f32x4 __attribute__((ext_vector_type(4)));
typedef __bf16 bf8v __attribute__((ext_vector_type(8)));

// d_ws byte offsets (unchanged vs R3 -> known to fit)
#define WS_ABF   0ULL                 // 67,108,864  hidden bf16; later bf16 tops
#define WS_WBF   67108864ULL          // 4,194,304   W_proj bf16
#define WS_PROJ  71303168ULL          // 134,217,728 proj = [h_all|v_all] bf16
#define WS_OP4   205520896ULL         // 524,288     op_probs padded float4
#define WS_WP    206045184ULL         // 4,194,304   interleaved (w,p) f32
#define WS_NEED  210239488ULL

// d_out float offsets
#define OUT_FINAL 0
#define OUT_STACK 33554432ULL         // (16,16,1024)
#define OUT_PTR   33816576ULL         // (16,16)
#define OUT_TOOLW 33816832ULL         // (16,2048,5)
// scratch inside the (not-yet-written) final region:
#define SLE_OFF   0ULL                // 16b x 32c x 16d x 1024h f32 = 8,388,608 floats
#define ATOT_OFF  30000000ULL         // 16b x 32c x 16d f32 = 8192 floats

__device__ __forceinline__ float bf2f(unsigned short u) {
    union { unsigned int i; float f; } v; v.i = ((unsigned int)u) << 16; return v.f;
}
__device__ __forceinline__ unsigned short f2bf(float f) {
    __hip_bfloat16 h = __float2bfloat16(f);
    return __builtin_bit_cast(unsigned short, h);
}
template<int C>
__device__ __forceinline__ float fdpp(float x) {
    return __int_as_float(__builtin_amdgcn_mov_dpp(__float_as_int(x), C, 0xF, 0xF, true));
}
__device__ __forceinline__ void gload_lds16(const void* g, void* l) {
    __builtin_amdgcn_global_load_lds(
        (__attribute__((address_space(1))) void*)(uintptr_t)g,
        (__attribute__((address_space(3))) void*)l,
        16, 0, 0);
}

// ---------------------------------------------------------------------------
// k0: hidden -> bf16 (A), W_proj -> bf16 (B), op_probs (f32).
// ---------------------------------------------------------------------------
__global__ __launch_bounds__(256) void k0(const float* __restrict__ hid,
                                          const float* __restrict__ Wp,
                                          const float* __restrict__ Wop,
                                          const float* __restrict__ bop,
                                          unsigned short* __restrict__ Abf,
                                          unsigned short* __restrict__ Wbf,
                                          float4* __restrict__ op4)
{
    const int bid = blockIdx.x, tid = threadIdx.x;
    if (bid < 8192) {
        const int wid = tid >> 6, lane = tid & 63;
        const int row = bid * 4 + wid;
        const float* hrow = hid + (size_t)row * 1024 + lane * 16;
        float xs[16];
        #pragma unroll
        for (int j = 0; j < 4; ++j) {
            float4 t = *(const float4*)(hrow + j * 4);
            xs[j*4+0] = t.x; xs[j*4+1] = t.y; xs[j*4+2] = t.z; xs[j*4+3] = t.w;
        }
        unsigned short us[16];
        #pragma unroll
        for (int j = 0; j < 16; ++j) us[j] = f2bf(xs[j]);
        uint4 ulo, uhi;
        ulo.x = (unsigned)us[0]  | ((unsigned)us[1]  << 16);
        ulo.y = (unsigned)us[2]  | ((unsigned)us[3]  << 16);
        ulo.z = (unsigned)us[4]  | ((unsigned)us[5]  << 16);
        ulo.w = (unsigned)us[6]  | ((unsigned)us[7]  << 16);
        uhi.x = (unsigned)us[8]  | ((unsigned)us[9]  << 16);
        uhi.y = (unsigned)us[10] | ((unsigned)us[11] << 16);
        uhi.z = (unsigned)us[12] | ((unsigned)us[13] << 16);
        uhi.w = (unsigned)us[14] | ((unsigned)us[15] << 16);
        unsigned short* arow = Abf + (size_t)row * 1024 + lane * 16;
        *(uint4*)(arow)     = ulo;
        *(uint4*)(arow + 8) = uhi;
        float pt[3] = {0.f, 0.f, 0.f};
        #pragma unroll
        for (int o = 0; o < 3; ++o) {
            const float* wrow = Wop + o * 1024 + lane * 16;
            #pragma unroll
            for (int j = 0; j < 4; ++j) {
                float4 t = *(const float4*)(wrow + j * 4);
                pt[o] += xs[j*4+0]*t.x + xs[j*4+1]*t.y + xs[j*4+2]*t.z + xs[j*4+3]*t.w;
            }
        }
        #pragma unroll
        for (int o = 0; o < 3; ++o)
            #pragma unroll
            for (int m = 32; m >= 1; m >>= 1) pt[o] += __shfl_xor(pt[o], m);
        if (lane == 0) {
            float l0 = pt[0] + bop[0], l1 = pt[1] + bop[1], l2 = pt[2] + bop[2];
            float mx = fmaxf(l0, fmaxf(l1, l2));
            float e0 = expf(l0 - mx), e1 = expf(l1 - mx), e2 = expf(l2 - mx);
            float inv = 1.0f / (e0 + e1 + e2);
            float4 r; r.x = e0 * inv; r.y = e1 * inv; r.z = e2 * inv; r.w = 0.f;
            op4[row] = r;
        }
    } else {
        const int b2 = bid - 8192;
        const size_t base = (size_t)b2 * 2048 + tid * 8;
        float4 a = *(const float4*)(Wp + base);
        float4 b = *(const float4*)(Wp + base + 4);
        unsigned short vs[8] = { f2bf(a.x), f2bf(a.y), f2bf(a.z), f2bf(a.w),
                                 f2bf(b.x), f2bf(b.y), f2bf(b.z), f2bf(b.w) };
        uint4 u;
        u.x = (unsigned)vs[0] | ((unsigned)vs[1] << 16);
        u.y = (unsigned)vs[2] | ((unsigned)vs[3] << 16);
        u.z = (unsigned)vs[4] | ((unsigned)vs[5] << 16);
        u.w = (unsigned)vs[6] | ((unsigned)vs[7] << 16);
        *(uint4*)(Wbf + base) = u;
    }
}

// ---------------------------------------------------------------------------
// k1: blocks 0..15 pointer scan (DPP over 16 lanes; writes (w,p) pairs and
//     per-chunk Atot = prod(1-w)); blocks 16..4111 bf16 MFMA GEMM 128x128.
// ---------------------------------------------------------------------------
__global__ __launch_bounds__(256) void k1(const unsigned short* __restrict__ Abf,
                                          const unsigned short* __restrict__ Wbf,
                                          const float* __restrict__ bproj,
                                          unsigned short* __restrict__ proj,
                                          const float4* __restrict__ op4,
                                          float* __restrict__ wpbuf,
                                          float* __restrict__ out)
{
    __shared__ uint4 sm[2048];   // 32 KiB
    const int bid = blockIdx.x, tid = threadIdx.x;

    if (bid < 16) {
        const int b = bid;
        #pragma unroll
        for (int i = 0; i < 8; ++i)
            sm[tid + i * 256] = ((const uint4*)op4)[(size_t)b * 2048 + tid + i * 256];
        __syncthreads();
        if (tid >= 64) return;               // wave 0 only from here
        __builtin_amdgcn_s_setprio(1);
        const int lane = tid, d = lane & 15;
        const float probe = (float)d;
        const bool ror1_is_push = (fdpp<0x121>(probe) == (float)((d + 15) & 15));
        float p = (d == 0) ? 1.0f : 0.0f;
        float Apre = 1.0f;
        const float4* smf = (const float4*)sm;
        float4 o0 = smf[0], o1 = smf[1];
        float* wpb = wpbuf + (size_t)b * 2048 * 32;
        float* atot = out + ATOT_OFF + (size_t)b * 32 * 16;
        #pragma unroll 2
        for (int s = 0; s < 2048; ++s) {
            float4 o2 = smf[(s + 2 < 2048) ? (s + 2) : 2047];
            const float push = o0.x, pop = o0.y, nop = o0.z;
            const float ra = fdpp<0x121>(p);
            const float rb = fdpp<0x12F>(p);
            const float ppush = ror1_is_push ? ra : rb;   // p[d-1]
            const float ppop  = ror1_is_push ? rb : ra;   // p[d+1]
            const float w = push * ppush;
            float lin = push * ppush + pop * ppop + nop * p;
            float x2 = lin * lin;
            float x5 = x2 * x2 * lin;
            float sum = x5;
            sum += fdpp<0x128>(sum);
            sum += fdpp<0x124>(sum);
            sum += fdpp<0x122>(sum);
            sum += fdpp<0x121>(sum);
            float pn = x5 * __builtin_amdgcn_rcpf(sum + 1e-8f);
            const float om = 1.0f - w;
            Apre = ((s & 63) == 0) ? om : Apre * om;
            if (lane < 16) {
                float2 wp; wp.x = w; wp.y = pn;
                *(float2*)(wpb + ((size_t)s * 16 + d) * 2) = wp;
                if ((s & 63) == 63) atot[(s >> 6) * 16 + d] = Apre;
            }
            p = pn;
            o0 = o1; o1 = o2;
        }
        if (lane < 16) out[OUT_PTR + (size_t)b * 16 + d] = p;
        return;
    }

    // ---- GEMM: proj[m,n] = sum_k A[m,k]*W[n,k] + b_proj[n] ----
    int bid2 = bid - 16;
    bid2 = (bid2 & 7) * 512 + (bid2 >> 3);     // XCD-contiguous (4096 % 8 == 0)
    const int gm = bid2 & 255;
    const int gn = bid2 >> 8;
    const int wid = tid >> 6, lane = tid & 63;
    const int wm = wid & 1, wn = wid >> 1;
    const size_t row0 = (size_t)gm * 128;
    const size_t col0 = (size_t)gn * 128;
    char* smc = (char*)sm;
    const char* Ab = (const char*)Abf;
    const char* Bb = (const char*)Wbf;
    f32x4 acc[4][4];
    const f32x4 z = {0.f, 0.f, 0.f, 0.f};
    #pragma unroll
    for (int i = 0; i < 4; ++i)
        #pragma unroll
        for (int j = 0; j < 4; ++j) acc[i][j] = z;

    for (int kt = 0; kt < 16; ++kt) {
        #pragma unroll
        for (int i = 0; i < 4; ++i) {
            const int off  = (i * 256 + tid) * 16;
            const int soff = off ^ (((off >> 7) & 7) << 4);
            gload_lds16(Ab + (row0 + (size_t)(soff >> 7)) * 2048 + (size_t)kt * 128 + (soff & 127),
                        smc + (i * 256 + wid * 64) * 16);
        }
        #pragma unroll
        for (int i = 0; i < 4; ++i) {
            const int off  = (i * 256 + tid) * 16;
            const int soff = off ^ (((off >> 7) & 7) << 4);
            gload_lds16(Bb + (col0 + (size_t)(soff >> 7)) * 2048 + (size_t)kt * 128 + (soff & 127),
                        smc + 16384 + (i * 256 + wid * 64) * 16);
        }
        __syncthreads();
        bf8v af[4][2], bfv[4][2];
        #pragma unroll
        for (int mr = 0; mr < 4; ++mr)
            #pragma unroll
            for (int kk = 0; kk < 2; ++kk) {
                int byt = (wm * 64 + mr * 16 + (lane & 15)) * 128 + kk * 64 + ((lane >> 4) * 16);
                byt ^= ((byt >> 7) & 7) << 4;
                af[mr][kk] = *(const bf8v*)(smc + byt);
            }
        #pragma unroll
        for (int nr = 0; nr < 4; ++nr)
            #pragma unroll
            for (int kk = 0; kk < 2; ++kk) {
                int byt = (wn * 64 + nr * 16 + (lane & 15)) * 128 + kk * 64 + ((lane >> 4) * 16);
                byt ^= ((byt >> 7) & 7) << 4;
                bfv[nr][kk] = *(const bf8v*)(smc + 16384 + byt);
            }
        #pragma unroll
        for (int mr = 0; mr < 4; ++mr)
            #pragma unroll
            for (int nr = 0; nr < 4; ++nr) {
                acc[mr][nr] = __builtin_amdgcn_mfma_f32_16x16x32_bf16(af[mr][0], bfv[nr][0], acc[mr][nr], 0, 0, 0);
                acc[mr][nr] = __builtin_amdgcn_mfma_f32_16x16x32_bf16(af[mr][1], bfv[nr][1], acc[mr][nr], 0, 0, 0);
            }
        __syncthreads();
    }
    #pragma unroll
    for (int mr = 0; mr < 4; ++mr) {
        const int rloc = wm * 64 + mr * 16 + ((lane >> 4) * 4);
        #pragma unroll
        for (int nr = 0; nr < 4; ++nr) {
            const size_t col = col0 + wn * 64 + nr * 16 + (lane & 15);
            const float bias = bproj[col];
            #pragma unroll
            for (int j = 0; j < 4; ++j)
                proj[(row0 + rloc + j) * 2048 + col] = f2bf(acc[mr][nr][j] + bias);
        }
    }
}

// ---------------------------------------------------------------------------
// k2 (pass 1): per-chunk local stack states with zero start.
// grid 2048 = 16 b x 32 c x 4 hg; 256 threads; thread owns one h, 16 d-slots.
// Writes sle[b][c][d][h] f32 into d_out final-region scratch. c==31 unused.
// ---------------------------------------------------------------------------
__global__ __launch_bounds__(256) void k2(const unsigned short* __restrict__ proj,
                                          const float* __restrict__ wpbuf,
                                          float* __restrict__ sle)
{
    __shared__ unsigned short vlds[2][4096];  // 2 x (16 s x 256 h) bf16 = 16 KiB
    const int bid = blockIdx.x, tid = threadIdx.x;
    const int hg = bid & 3, c = (bid >> 2) & 31, b = bid >> 7;
    if (c == 31) return;    // sle(31) never consumed
    const int wid = tid >> 6;
    const char* vbase = (const char*)proj +
        ((size_t)(b * 2048 + c * 64) * 2048 + 1024 + hg * 256) * 2;
    const float* wpb = wpbuf + ((size_t)b * 2048 + c * 64) * 32;

    float st[16];
    #pragma unroll
    for (int d = 0; d < 16; ++d) st[d] = 0.f;

    auto STAGE = [&](int sc, int buf) {
        #pragma unroll
        for (int i = 0; i < 2; ++i) {
            const int g = i * 256 + tid;
            gload_lds16(vbase + (size_t)(sc * 16 + (g >> 5)) * 4096 + (g & 31) * 16,
                        (char*)vlds + buf * 8192 + (i * 256 + wid * 64) * 16);
        }
    };
    STAGE(0, 0);
    __syncthreads();
    for (int sc = 0; sc < 4; ++sc) {
        const int cur = sc & 1;
        if (sc < 3) STAGE(sc + 1, cur ^ 1);
        const unsigned short* vl = vlds[cur];
        #pragma unroll 4
        for (int ls = 0; ls < 16; ++ls) {
            const float v = bf2f(vl[ls * 256 + tid]);
            const float4* wp4 = (const float4*)(wpb + (size_t)(sc * 16 + ls) * 32);
            #pragma unroll
            for (int k = 0; k < 8; ++k) {
                float4 q = wp4[k];                    // w[2k],p[2k],w[2k+1],p[2k+1]
                st[2*k]   = fmaf(q.x, v - st[2*k],   st[2*k]);
                st[2*k+1] = fmaf(q.z, v - st[2*k+1], st[2*k+1]);
            }
        }
        __syncthreads();
    }
    float* so = sle + ((size_t)b * 32 + c) * 16 * 1024 + hg * 256 + tid;
    #pragma unroll
    for (int d = 0; d < 16; ++d) so[(size_t)d * 1024] = st[d];
}

// ---------------------------------------------------------------------------
// k3 (pass 2): compose true chunk-start state from (Atot, sle) pairs, replay
// chunk emitting tops (bf16 -> Abf region); c==31 blocks write final stack.
// ---------------------------------------------------------------------------
__global__ __launch_bounds__(256) void k3(const unsigned short* __restrict__ proj,
                                          const float* __restrict__ wpbuf,
                                          const float* __restrict__ sle,
                                          const float* __restrict__ atot,
                                          unsigned short* __restrict__ tops,
                                          float* __restrict__ out)
{
    __shared__ unsigned short vlds[2][4096];
    const int bid = blockIdx.x, tid = threadIdx.x;
    const int hg = bid & 3, c = (bid >> 2) & 31, b = bid >> 7;
    const int wid = tid >> 6;
    const char* vbase = (const char*)proj +
        ((size_t)(b * 2048 + c * 64) * 2048 + 1024 + hg * 256) * 2;
    const float* wpb = wpbuf + ((size_t)b * 2048 + c * 64) * 32;

    float st[16];
    #pragma unroll
    for (int d = 0; d < 16; ++d) st[d] = 0.f;

    // carry composition: st_start(c) via c' = 0..c-1
    {
        const float* sb = sle + (size_t)b * 32 * 16 * 1024 + hg * 256 + tid;
        const float* ab = atot + (size_t)b * 32 * 16;
        for (int cp = 0; cp < c; ++cp) {
            #pragma unroll
            for (int d = 0; d < 16; ++d)
                st[d] = fmaf(ab[cp * 16 + d], st[d],
                             sb[((size_t)cp * 16 + d) * 1024]);
        }
    }

    unsigned short* topb = tops + ((size_t)b * 2048 + c * 64) * 1024 + hg * 256 + tid;

    auto STAGE = [&](int sc, int buf) {
        #pragma unroll
        for (int i = 0; i < 2; ++i) {
            const int g = i * 256 + tid;
            gload_lds16(vbase + (size_t)(sc * 16 + (g >> 5)) * 4096 + (g & 31) * 16,
                        (char*)vlds + buf * 8192 + (i * 256 + wid * 64) * 16);
        }
    };
    STAGE(0, 0);
    __syncthreads();
    for (int sc = 0; sc < 4; ++sc) {
        const int cur = sc & 1;
        if (sc < 3) STAGE(sc + 1, cur ^ 1);
        const unsigned short* vl = vlds[cur];
        #pragma unroll 4
        for (int ls = 0; ls < 16; ++ls) {
            const float v = bf2f(vl[ls * 256 + tid]);
            const float4* wp4 = (const float4*)(wpb + (size_t)(sc * 16 + ls) * 32);
            float t0 = 0.f, t1 = 0.f;
            #pragma unroll
            for (int k = 0; k < 8; ++k) {
                float4 q = wp4[k];
                st[2*k]   = fmaf(q.x, v - st[2*k],   st[2*k]);
                st[2*k+1] = fmaf(q.z, v - st[2*k+1], st[2*k+1]);
                t0 = fmaf(q.y, st[2*k],   t0);
                t1 = fmaf(q.w, st[2*k+1], t1);
            }
            topb[(size_t)(sc * 16 + ls) * 1024] = f2bf(t0 + t1);
        }
        __syncthreads();
    }
    if (c == 31) {
        #pragma unroll
        for (int d = 0; d < 16; ++d)
            out[OUT_STACK + ((size_t)b * 16 + d) * 1024 + hg * 256 + tid] = st[d];
    }
}

// ---------------------------------------------------------------------------
// k5: epilogue per (b,s) row: tool softmax, apply tools, residual, LayerNorm.
// ---------------------------------------------------------------------------
__global__ __launch_bounds__(256) void k5(const unsigned short* __restrict__ proj,
                                          const unsigned short* __restrict__ tops,
                                          const float* __restrict__ hid,
                                          const float* __restrict__ Wtool,
                                          const float* __restrict__ btool,
                                          const float* __restrict__ gamma,
                                          const float* __restrict__ beta,
                                          float* __restrict__ out)
{
    __shared__ float red[4][8];
    const int row = blockIdx.x, tid = threadIdx.x;
    const int wid = tid >> 6, lane = tid & 63;
    const int k0i = tid * 4;
    uint2 hu = *(const uint2*)(proj + (size_t)row * 2048 + k0i);
    float hh[4];
    hh[0] = bf2f(hu.x & 0xffff); hh[1] = bf2f(hu.x >> 16);
    hh[2] = bf2f(hu.y & 0xffff); hh[3] = bf2f(hu.y >> 16);
    uint2 tu = *(const uint2*)(tops + (size_t)row * 1024 + k0i);
    float xs[4];
    xs[0] = bf2f(tu.x & 0xffff); xs[1] = bf2f(tu.x >> 16);
    xs[2] = bf2f(tu.y & 0xffff); xs[3] = bf2f(tu.y >> 16);
    float4 hd4 = *(const float4*)(hid + (size_t)row * 1024 + k0i);
    float hds[4] = {hd4.x, hd4.y, hd4.z, hd4.w};
    float pt[5];
    #pragma unroll
    for (int t = 0; t < 5; ++t) {
        float4 wv = *(const float4*)(Wtool + t * 1024 + k0i);
        pt[t] = hh[0]*wv.x + hh[1]*wv.y + hh[2]*wv.z + hh[3]*wv.w;
    }
    #pragma unroll
    for (int t = 0; t < 5; ++t)
        #pragma unroll
        for (int m = 32; m >= 1; m >>= 1) pt[t] += __shfl_xor(pt[t], m);
    if (lane == 0) {
        #pragma unroll
        for (int t = 0; t < 5; ++t) red[wid][t] = pt[t];
    }
    __syncthreads();
    float tw[5];
    {
        float lg[5];
        #pragma unroll
        for (int t = 0; t < 5; ++t)
            lg[t] = red[0][t] + red[1][t] + red[2][t] + red[3][t] + btool[t];
        float mx = fmaxf(fmaxf(fmaxf(lg[0], lg[1]), fmaxf(lg[2], lg[3])), lg[4]);
        float se = 0.f;
        #pragma unroll
        for (int t = 0; t < 5; ++t) { tw[t] = expf(lg[t] - mx); se += tw[t]; }
        float inv = 1.0f / se;
        #pragma unroll
        for (int t = 0; t < 5; ++t) tw[t] *= inv;
    }
    if (tid < 5) out[OUT_TOOLW + (size_t)row * 5 + tid] = tw[tid];
    float cj[4];
    #pragma unroll
    for (int j = 0; j < 4; ++j) {
        const float x = xs[j];
        const float rl = fmaxf(x, 0.f);
        const float gl = 0.5f * x * (1.f + erff(x * 0.70710678118654752f));
        const float th = tanhf(x);
        const float sg = 1.f / (1.f + expf(-x));
        const float pr = rl*tw[0] + gl*tw[1] + th*tw[2] + sg*tw[3] + x*tw[4];
        cj[j] = hh[j] + pr + hds[j];
    }
    float s1 = cj[0] + cj[1] + cj[2] + cj[3];
    float s2 = cj[0]*cj[0] + cj[1]*cj[1] + cj[2]*cj[2] + cj[3]*cj[3];
    #pragma unroll
    for (int m = 32; m >= 1; m >>= 1) { s1 += __shfl_xor(s1, m); s2 += __shfl_xor(s2, m); }
    __syncthreads();
    if (lane == 0) { red[wid][0] = s1; red[wid][1] = s2; }
    __syncthreads();
    const float S1 = red[0][0] + red[1][0] + red[2][0] + red[3][0];
    const float S2 = red[0][1] + red[1][1] + red[2][1] + red[3][1];
    const float mu = S1 * (1.f / 1024.f);
    const float var = S2 * (1.f / 1024.f) - mu * mu;
    const float rstd = rsqrtf(var + 1e-5f);
    float4 g4 = *(const float4*)(gamma + k0i);
    float4 b4 = *(const float4*)(beta + k0i);
    float4 res;
    res.x = (cj[0] - mu) * rstd * g4.x + b4.x;
    res.y = (cj[1] - mu) * rstd * g4.y + b4.y;
    res.z = (cj[2] - mu) * rstd * g4.z + b4.z;
    res.w = (cj[3] - mu) * rstd * g4.w + b4.w;
    *(float4*)(out + (size_t)row * 1024 + k0i) = res;
}

extern "C" void kernel_launch(void* const* d_in, const int* in_sizes, int n_in,
                              void* d_out, int out_size, void* d_ws, size_t ws_size,
                              hipStream_t stream)
{
    if (ws_size < WS_NEED) {
        fprintf(stderr, "kernel_launch: ws_size %zu < required %llu\n",
                ws_size, (unsigned long long)WS_NEED);
        return;
    }
    const float* hid = (const float*)d_in[0];
    const float* Wp  = (const float*)d_in[1];
    const float* bp  = (const float*)d_in[2];
    const float* Wop = (const float*)d_in[3];
    const float* bop = (const float*)d_in[4];
    const float* Wtl = (const float*)d_in[5];
    const float* btl = (const float*)d_in[6];
    const float* gam = (const float*)d_in[7];
    const float* bet = (const float*)d_in[8];
    float* out = (float*)d_out;
    char* ws = (char*)d_ws;
    unsigned short* Abf  = (unsigned short*)(ws + WS_ABF);   // hidden bf16, then tops bf16
    unsigned short* Wbf  = (unsigned short*)(ws + WS_WBF);
    unsigned short* proj = (unsigned short*)(ws + WS_PROJ);
    float4* op4 = (float4*)(ws + WS_OP4);
    float* wpbuf = (float*)(ws + WS_WP);
    float* sle  = out + SLE_OFF;
    float* atot = out + ATOT_OFF;

    k0<<<9216, 256, 0, stream>>>(hid, Wp, Wop, bop, Abf, Wbf, op4);
    k1<<<4112, 256, 0, stream>>>(Abf, Wbf, bp, proj, op4, wpbuf, out);
    k2<<<2048, 256, 0, stream>>>(proj, wpbuf, sle);
    k3<<<2048, 256, 0, stream>>>(proj, wpbuf, sle, atot, Abf, out);
    k5<<<32768, 256, 0, stream>>>(proj, Abf, hid, Wtl, btl, gam, bet, out);
}